// Round 13
// baseline (81.980 us; speedup 1.0000x reference)
//
#include <hip/hip_runtime.h>

// Problem constants
constexpr int T_    = 4096;
constexpr int DH_   = 128;
constexpr int NB_   = 32;    // buckets
constexpr int BSZ_  = 128;   // bucket size
constexpr int HH_   = 4;     // H/2 (rotated heads start here)
constexpr int H_    = 8;
constexpr int BH_   = 32;    // B*H

typedef __attribute__((ext_vector_type(8))) short short8;
typedef __attribute__((ext_vector_type(4))) float f32x4;
typedef __attribute__((ext_vector_type(4))) unsigned int u32x4;

__device__ __forceinline__ unsigned int cvt_pk_bf16(float lo, float hi) {
  unsigned int r;
  asm("v_cvt_pk_bf16_f32 %0, %1, %2" : "=v"(r) : "v"(lo), "v"(hi));
  return r;
}

// ---------------- Kernel A1: per-bucket column sums + first row of each bucket ----------
__global__ __launch_bounds__(256)
void k_bucket_sums(const float* __restrict__ k,
                   float* __restrict__ bucketsum,
                   float* __restrict__ firstrow) {
  __shared__ float4 red[8][32];
  int blk = blockIdx.x;           // (b*H + h)*NB + u
  int u = blk & (NB_ - 1);
  int bh = blk >> 5;
  int h = bh & (H_ - 1);
  bool rot = (h >= HH_);
  int tid = threadIdx.x;
  int rq = tid >> 5;              // 0..7
  int l  = tid & 31;              // 0..31
  int d0 = l * 4;
  const float* kb = k + (size_t)bh * T_ * DH_;

  float4 s = {0.f, 0.f, 0.f, 0.f};
  float4 first = {0.f, 0.f, 0.f, 0.f};
  #pragma unroll
  for (int it = 0; it < 16; ++it) {
    int i = it * 8 + rq;
    int t = u * BSZ_ + i;
    if (rot) t = (t + (BSZ_ - 1)) & (T_ - 1);
    float4 a = *(const float4*)(kb + (size_t)t * DH_ + d0);
    s.x += a.x; s.y += a.y; s.z += a.z; s.w += a.w;
    if (it == 0 && rq == 0) first = a;
  }
  red[rq][l] = s;
  __syncthreads();
  if (rq == 0) {
    float4 acc = {0.f, 0.f, 0.f, 0.f};
    #pragma unroll
    for (int j = 0; j < 8; ++j) {
      float4 a = red[j][l];
      acc.x += a.x; acc.y += a.y; acc.z += a.z; acc.w += a.w;
    }
    *(float4*)(bucketsum + (size_t)blk * DH_ + d0) = acc;
    *(float4*)(firstrow  + (size_t)blk * DH_ + d0) = first;
  }
}

// ---------------- Kernel A2: routing matrix R -> (scale, idx) packed float2 -------------
__global__ __launch_bounds__(256)
void k_routing(const float* __restrict__ W,
               const float* __restrict__ bucketsum,
               const float* __restrict__ firstrow,
               float2* __restrict__ scIdx) {
  __shared__ float Wl[2 * DH_ * NB_];      // [e][v] row-major, 8192 floats
  __shared__ float Xl[NB_][2 * DH_ + 1];   // padded
  __shared__ float Rl[NB_][36];            // 36-float rows: 16B aligned
  int bh = blockIdx.x;
  int h = bh & (H_ - 1);
  int tid = threadIdx.x;                   // 256 threads

  const float4* Wg = (const float4*)(W + (size_t)h * 2 * DH_ * NB_);
  #pragma unroll
  for (int rep = 0; rep < 8; ++rep)
    ((float4*)Wl)[tid + rep * 256] = Wg[tid + rep * 256];

  if (tid < DH_) {
    int d = tid;
    float S = 0.f;
    for (int u = 0; u < NB_; ++u) {
      float fr = firstrow [((size_t)bh * NB_ + u) * DH_ + d];
      float bs = bucketsum[((size_t)bh * NB_ + u) * DH_ + d];
      Xl[u][d]        = (S + fr) / (float)(u * BSZ_ + 1);
      Xl[u][DH_ + d]  = fr;
      S += bs;
    }
  }
  __syncthreads();

  {
    int u = tid >> 3;
    int vg = tid & 7;
    float4 racc = {0.f, 0.f, 0.f, 0.f};
    for (int e = 0; e < 2 * DH_; ++e) {
      float xv = Xl[u][e];
      float4 wv = *(const float4*)(Wl + e * NB_ + vg * 4);
      racc.x += xv * wv.x; racc.y += xv * wv.y;
      racc.z += xv * wv.z; racc.w += xv * wv.w;
    }
    racc.x = (racc.x > 0.f) ? racc.x : 0.01f * racc.x;
    racc.y = (racc.y > 0.f) ? racc.y : 0.01f * racc.y;
    racc.z = (racc.z > 0.f) ? racc.z : 0.01f * racc.z;
    racc.w = (racc.w > 0.f) ? racc.w : 0.01f * racc.w;
    *(float4*)(&Rl[u][vg * 4]) = racc;
  }
  __syncthreads();

  if (tid < NB_) {
    int u = tid;
    float m = -3.4e38f;
    float r[NB_];
    #pragma unroll
    for (int v = 0; v < NB_; ++v) { r[v] = Rl[u][v]; m = fmaxf(m, r[v]); }
    float Z = 0.f;
    #pragma unroll
    for (int v = 0; v < NB_; ++v) Z += expf(r[v] - m);
    float best = -3.4e38f; int bi = 0;
    for (int v = 0; v < u; ++v) {        // tril(-1): only v < u survive
      if (r[v] > best) { best = r[v]; bi = v; }
    }
    float sc = (u == 0) ? 0.f : expf(best - m) / Z;
    int  idx = (u == 0) ? 0 : bi;
    scIdx[bh * NB_ + u] = make_float2(sc, __int_as_float(idx));
  }
}

// ---------------- Kernel B: R12 + early PV1 (S2b) + u==0 half skip ---------------------
// RA 32KB: K1(sc*src) -> VT1(sc*src). RB 32KB: K2(own) -> VT2(own).
// Order: stageK -> S1 -> QK -> S2 -> VT1 -> S2b -> softmax -> pack -> PV1(RA)
//        -> VT2 -> S3 -> PV2(RB) -> store.  u==0 (sc=0): skip K1/VT1/QK1/PV1.
__global__ __launch_bounds__(512, 4)
void k_attn(const float* __restrict__ q, const float* __restrict__ k,
            const float* __restrict__ v, const float2* __restrict__ scIdx,
            float* __restrict__ out) {
  __shared__ __align__(16) unsigned short RA[128 * 128];   // 32KB
  __shared__ __align__(16) unsigned short RB[128 * 128];   // 32KB

  int blk0 = blockIdx.x;
  int blk  = ((blk0 & 7) << 7) | (blk0 >> 3);  // XCD-chunked swizzle (1024 = 8*128)
  int u  = blk & (NB_ - 1);
  int bh = blk >> 5;
  int h  = bh & (H_ - 1);
  bool rot = (h >= HH_);
  float2 si = scIdx[bh * NB_ + u];
  float sc = si.x;
  int  src = __float_as_int(si.y);
  const size_t base = (size_t)bh * T_ * DH_;
  const bool half1 = (u != 0);    // u==0: sc=0 -> first half contributes zero scores & zero V

  int tid  = threadIdx.x;
  int lane = tid & 63;
  int w    = tid >> 6;        // wave 0..7, owns q-rows [16w, 16w+16)
  int g    = lane >> 4;       // 0..3
  int c    = lane & 15;       // 0..15

  const float QSCALE = 0.03125f * 1.44269504f;   // d^-0.5 * log2e folded into Q

  // ---- Q fragments (B-operand: col = c -> i = 16w + c), pre-scaled ----
  short8 qf[4];
  {
    int t = u * BSZ_ + 16 * w + c;
    if (rot) t = (t + (BSZ_ - 1)) & (T_ - 1);
    const float* qrow = q + base + (size_t)t * DH_;
    #pragma unroll
    for (int kt = 0; kt < 4; ++kt) {
      f32x4 a = *(const f32x4*)(qrow + kt * 32 + g * 8) * QSCALE;
      f32x4 b = *(const f32x4*)(qrow + kt * 32 + g * 8 + 4) * QSCALE;
      u32x4 tt;
      tt.x = cvt_pk_bf16(a[0], a[1]);
      tt.y = cvt_pk_bf16(a[2], a[3]);
      tt.z = cvt_pk_bf16(b[0], b[1]);
      tt.w = cvt_pk_bf16(b[2], b[3]);
      qf[kt] = __builtin_bit_cast(short8, tt);
    }
  }

  // ---- Stage K halves: K1 = sc*k[src] -> RA (skip if u==0), K2 = k[u] -> RB ----
  #pragma unroll
  for (int rep = 0; rep < 16; ++rep) {
    int chunk = tid + rep * 512;          // 8192 chunks of 4 floats
    int jr = chunk >> 5;                  // 0..255
    int c0 = (chunk & 31) * 4;
    if (jr < BSZ_ && !half1) continue;    // u==0: RA never read
    int t; float mul;
    if (jr < BSZ_) { t = src * BSZ_ + jr;         mul = sc;  }
    else           { t = u  * BSZ_ + (jr - BSZ_); mul = 1.f; }
    if (rot) t = (t + (BSZ_ - 1)) & (T_ - 1);
    f32x4 a = *(const f32x4*)(k + base + (size_t)t * DH_ + c0) * mul;
    uint2 wv;
    wv.x = cvt_pk_bf16(a[0], a[1]);
    wv.y = cvt_pk_bf16(a[2], a[3]);
    unsigned short* Rg = (jr < BSZ_) ? RA : RB;
    int row = jr & 127;
    *(uint2*)((char*)Rg + row * 256 + ((c0 * 2) ^ ((row & 15) << 4))) = wv;
  }
  __syncthreads();   // S1

  // ---- VT staging: load -> convert -> commit immediately (transient regs only) ----
  // Column permute within each 32-j block: jc = (j&~31) | 8*((j>>2)&3) | 4*((j>>4)&1) | (j&3)
  auto vt_stage = [&](int sb, float mul, unsigned short* Rg) {
    #pragma unroll
    for (int rep = 0; rep < 2; ++rep) {
      int j0 = ((tid >> 5) + rep * 16) * 4;
      int jc0 = (j0 & ~31) | (((j0 >> 2) & 3) << 3) | (((j0 >> 4) & 1) << 2);
      int d0 = (tid & 31) * 4;
      f32x4 rr[4];
      #pragma unroll
      for (int jj = 0; jj < 4; ++jj) {
        int t = sb * BSZ_ + j0 + jj;
        if (rot) t = (t + (BSZ_ - 1)) & (T_ - 1);
        rr[jj] = *(const f32x4*)(v + base + (size_t)t * DH_ + d0) * mul;
      }
      #pragma unroll
      for (int m = 0; m < 4; ++m) {
        uint2 wv;
        wv.x = cvt_pk_bf16(rr[0][m], rr[1][m]);
        wv.y = cvt_pk_bf16(rr[2][m], rr[3][m]);
        int row = d0 + m;
        *(uint2*)((char*)Rg + row * 256 + ((jc0 * 2) ^ ((row & 15) << 4))) = wv;
      }
    }
  };

  const bool lastrot = rot && (u == NB_ - 1);
  const int i = 16 * w + c;
  const bool killLow = lastrot && (i > 0);

  // ---- QK^T swapped: acc[jt][r] = S[j = 16jt+4g+r][i = 16w+c]; skip jt > 8+w ----
  f32x4 acc[16];
  #pragma unroll
  for (int jt = 0; jt < 16; ++jt) acc[jt] = f32x4{0.f, 0.f, 0.f, 0.f};

  __builtin_amdgcn_s_setprio(1);
  #pragma unroll
  for (int kt = 0; kt < 4; ++kt) {
    #pragma unroll
    for (int jt = 0; jt < 16; ++jt) {
      if (jt <= 8 + w) {
        if (jt < 8 && !half1) continue;   // u==0: scores are exactly 0 (acc stays 0)
        const unsigned short* Rg = (jt < 8) ? RA : RB;
        int row = (jt & 7) * 16 + c;
        short8 bfr = *(const short8*)((const char*)Rg + row * 256 + ((kt * 64 + g * 16) ^ ((row & 15) << 4)));
        acc[jt] = __builtin_amdgcn_mfma_f32_16x16x32_bf16(bfr, qf[kt], acc[jt], 0, 0, 0);
      }
    }
  }
  __builtin_amdgcn_s_setprio(0);

  __syncthreads();   // S2 (K reads done; RA/RB free)

  if (half1) vt_stage(src, sc, RA);   // VT1 = sc*v[src] -> RA
  __syncthreads();   // S2b (VT1 committed; PV1 may run after local softmax/pack)

  // ---- mask + softmax (scores fully pre-scaled); skipped tiles stay 0 ----
  float mx = -3.4e38f;
  #pragma unroll
  for (int jt = 0; jt < 16; ++jt) {
    if (jt <= 8 + w) {
      #pragma unroll
      for (int r = 0; r < 4; ++r) {
        float s = acc[jt][r];
        bool vis;
        if (jt < 8) {
          vis = !killLow;
        } else {
          int jb = 16 * (jt - 8) + 4 * g + r;
          vis = (i >= jb);
          if (jt == 8) vis = vis && !(killLow && (g == 0) && (r == 0));
        }
        s = vis ? s : -3.4e38f;
        acc[jt][r] = s;
        mx = fmaxf(mx, s);
      }
    }
  }
  mx = fmaxf(mx, __shfl_xor(mx, 16));
  mx = fmaxf(mx, __shfl_xor(mx, 32));
  float zs = 0.f;
  #pragma unroll
  for (int jt = 0; jt < 16; ++jt) {
    if (jt <= 8 + w) {
      #pragma unroll
      for (int r = 0; r < 4; ++r) {
        float p = exp2f(acc[jt][r] - mx);
        acc[jt][r] = p;
        zs += p;
      }
    }
  }
  zs += __shfl_xor(zs, 16);
  zs += __shfl_xor(zs, 32);
  float rz = 1.f / zs;

  // ---- P A-frags: register repack, uniform rz; skip fully-masked own-half m ----
  short8 pa[8];
  #pragma unroll
  for (int m = 0; m < 8; ++m) {
    if (m < 4 || (m - 4) <= (w >> 1)) {
      u32x4 tt;
      tt.x = cvt_pk_bf16(acc[2 * m][0] * rz,     acc[2 * m][1] * rz);
      tt.y = cvt_pk_bf16(acc[2 * m][2] * rz,     acc[2 * m][3] * rz);
      tt.z = cvt_pk_bf16(acc[2 * m + 1][0] * rz, acc[2 * m + 1][1] * rz);
      tt.w = cvt_pk_bf16(acc[2 * m + 1][2] * rz, acc[2 * m + 1][3] * rz);
      pa[m] = __builtin_bit_cast(short8, tt);
    }
  }

  // ---- PV half1 (RA, VT1) — before S3; accumulate into acc[0..7] ----
  #pragma unroll
  for (int nt = 0; nt < 8; ++nt) acc[nt] = f32x4{0.f, 0.f, 0.f, 0.f};

  if (half1) {
    __builtin_amdgcn_s_setprio(1);
    #pragma unroll
    for (int m = 0; m < 4; ++m) {
      #pragma unroll
      for (int nt = 0; nt < 8; ++nt) {
        int vrow = nt * 16 + c;
        short8 vb = *(const short8*)((const char*)RA + vrow * 256 + ((m * 64 + g * 16) ^ ((vrow & 15) << 4)));
        acc[nt] = __builtin_amdgcn_mfma_f32_16x16x32_bf16(pa[m], vb, acc[nt], 0, 0, 0);
      }
    }
    __builtin_amdgcn_s_setprio(0);
  }

  vt_stage(u, 1.f, RB);        // VT2 = v[u] -> RB (overlaps other waves' PV1 / softmax)
  __syncthreads();   // S3

  // ---- PV half2 (RB, VT2); skip own-half m with all-zero P ----
  __builtin_amdgcn_s_setprio(1);
  #pragma unroll
  for (int m = 4; m < 8; ++m) {
    if ((m - 4) <= (w >> 1)) {
      int mloc = m & 3;
      #pragma unroll
      for (int nt = 0; nt < 8; ++nt) {
        int vrow = nt * 16 + c;
        short8 vb = *(const short8*)((const char*)RB + vrow * 256 + ((mloc * 64 + g * 16) ^ ((vrow & 15) << 4)));
        acc[nt] = __builtin_amdgcn_mfma_f32_16x16x32_bf16(pa[m], vb, acc[nt], 0, 0, 0);
      }
    }
  }
  __builtin_amdgcn_s_setprio(0);

  // ---- store (undo rotation); acc[nt][r] = O[i=16w+4g+r][d=16nt+c] ----
  #pragma unroll
  for (int r = 0; r < 4; ++r) {
    int il = 4 * g + r;
    int t = u * BSZ_ + 16 * w + il;
    if (rot) t = (t + (BSZ_ - 1)) & (T_ - 1);
    float* orow = out + base + (size_t)t * DH_;
    #pragma unroll
    for (int nt = 0; nt < 8; ++nt) {
      orow[nt * 16 + c] = acc[nt][r];
    }
  }
}

extern "C" void kernel_launch(void* const* d_in, const int* in_sizes, int n_in,
                              void* d_out, int out_size, void* d_ws, size_t ws_size,
                              hipStream_t stream) {
  const float* q = (const float*)d_in[0];
  const float* k = (const float*)d_in[1];
  const float* v = (const float*)d_in[2];
  const float* W = (const float*)d_in[3];
  float* out = (float*)d_out;

  float*  bucketsum = (float*)d_ws;                 // 131072 floats
  float*  firstrow  = bucketsum + 131072;           // 131072 floats
  float2* scIdx     = (float2*)(firstrow + 131072); // 1024 float2

  k_bucket_sums<<<BH_ * NB_, 256, 0, stream>>>(k, bucketsum, firstrow);
  k_routing<<<BH_, 256, 0, stream>>>(W, bucketsum, firstrow, scIdx);
  k_attn<<<BH_ * NB_, 512, 0, stream>>>(q, k, v, scIdx, out);
}

// Round 14
// 76.069 us; speedup vs baseline: 1.0777x; 1.0777x over previous
//
#include <hip/hip_runtime.h>

// Problem constants
constexpr int T_    = 4096;
constexpr int DH_   = 128;
constexpr int NB_   = 32;    // buckets
constexpr int BSZ_  = 128;   // bucket size
constexpr int HH_   = 4;     // H/2 (rotated heads start here)
constexpr int H_    = 8;
constexpr int BH_   = 32;    // B*H

typedef __attribute__((ext_vector_type(8))) short short8;
typedef __attribute__((ext_vector_type(4))) float f32x4;
typedef __attribute__((ext_vector_type(4))) unsigned int u32x4;

__device__ __forceinline__ unsigned int cvt_pk_bf16(float lo, float hi) {
  unsigned int r;
  asm("v_cvt_pk_bf16_f32 %0, %1, %2" : "=v"(r) : "v"(lo), "v"(hi));
  return r;
}

// ---------------- Kernel A1: per-bucket column sums + first row of each bucket ----------
__global__ __launch_bounds__(256)
void k_bucket_sums(const float* __restrict__ k,
                   float* __restrict__ bucketsum,
                   float* __restrict__ firstrow) {
  __shared__ float4 red[8][32];
  int blk = blockIdx.x;           // (b*H + h)*NB + u
  int u = blk & (NB_ - 1);
  int bh = blk >> 5;
  int h = bh & (H_ - 1);
  bool rot = (h >= HH_);
  int tid = threadIdx.x;
  int rq = tid >> 5;              // 0..7
  int l  = tid & 31;              // 0..31
  int d0 = l * 4;
  const float* kb = k + (size_t)bh * T_ * DH_;

  float4 s = {0.f, 0.f, 0.f, 0.f};
  float4 first = {0.f, 0.f, 0.f, 0.f};
  #pragma unroll
  for (int it = 0; it < 16; ++it) {
    int i = it * 8 + rq;
    int t = u * BSZ_ + i;
    if (rot) t = (t + (BSZ_ - 1)) & (T_ - 1);
    float4 a = *(const float4*)(kb + (size_t)t * DH_ + d0);
    s.x += a.x; s.y += a.y; s.z += a.z; s.w += a.w;
    if (it == 0 && rq == 0) first = a;
  }
  red[rq][l] = s;
  __syncthreads();
  if (rq == 0) {
    float4 acc = {0.f, 0.f, 0.f, 0.f};
    #pragma unroll
    for (int j = 0; j < 8; ++j) {
      float4 a = red[j][l];
      acc.x += a.x; acc.y += a.y; acc.z += a.z; acc.w += a.w;
    }
    *(float4*)(bucketsum + (size_t)blk * DH_ + d0) = acc;
    *(float4*)(firstrow  + (size_t)blk * DH_ + d0) = first;
  }
}

// ---------------- Kernel A2: routing matrix R -> (scale, idx) packed float2 -------------
__global__ __launch_bounds__(256)
void k_routing(const float* __restrict__ W,
               const float* __restrict__ bucketsum,
               const float* __restrict__ firstrow,
               float2* __restrict__ scIdx) {
  __shared__ float Wl[2 * DH_ * NB_];      // [e][v] row-major, 8192 floats
  __shared__ float Xl[NB_][2 * DH_ + 1];   // padded
  __shared__ float Rl[NB_][36];            // 36-float rows: 16B aligned
  int bh = blockIdx.x;
  int h = bh & (H_ - 1);
  int tid = threadIdx.x;                   // 256 threads

  const float4* Wg = (const float4*)(W + (size_t)h * 2 * DH_ * NB_);
  #pragma unroll
  for (int rep = 0; rep < 8; ++rep)
    ((float4*)Wl)[tid + rep * 256] = Wg[tid + rep * 256];

  if (tid < DH_) {
    int d = tid;
    float S = 0.f;
    for (int u = 0; u < NB_; ++u) {
      float fr = firstrow [((size_t)bh * NB_ + u) * DH_ + d];
      float bs = bucketsum[((size_t)bh * NB_ + u) * DH_ + d];
      Xl[u][d]        = (S + fr) / (float)(u * BSZ_ + 1);
      Xl[u][DH_ + d]  = fr;
      S += bs;
    }
  }
  __syncthreads();

  {
    int u = tid >> 3;
    int vg = tid & 7;
    float4 racc = {0.f, 0.f, 0.f, 0.f};
    for (int e = 0; e < 2 * DH_; ++e) {
      float xv = Xl[u][e];
      float4 wv = *(const float4*)(Wl + e * NB_ + vg * 4);
      racc.x += xv * wv.x; racc.y += xv * wv.y;
      racc.z += xv * wv.z; racc.w += xv * wv.w;
    }
    racc.x = (racc.x > 0.f) ? racc.x : 0.01f * racc.x;
    racc.y = (racc.y > 0.f) ? racc.y : 0.01f * racc.y;
    racc.z = (racc.z > 0.f) ? racc.z : 0.01f * racc.z;
    racc.w = (racc.w > 0.f) ? racc.w : 0.01f * racc.w;
    *(float4*)(&Rl[u][vg * 4]) = racc;
  }
  __syncthreads();

  if (tid < NB_) {
    int u = tid;
    float m = -3.4e38f;
    float r[NB_];
    #pragma unroll
    for (int v = 0; v < NB_; ++v) { r[v] = Rl[u][v]; m = fmaxf(m, r[v]); }
    float Z = 0.f;
    #pragma unroll
    for (int v = 0; v < NB_; ++v) Z += expf(r[v] - m);
    float best = -3.4e38f; int bi = 0;
    for (int v = 0; v < u; ++v) {        // tril(-1): only v < u survive
      if (r[v] > best) { best = r[v]; bi = v; }
    }
    float sc = (u == 0) ? 0.f : expf(best - m) / Z;
    int  idx = (u == 0) ? 0 : bi;
    scIdx[bh * NB_ + u] = make_float2(sc, __int_as_float(idx));
  }
}

// ---------------- Kernel B: R12 + unnormalized P, rz applied post-PV -------------------
// RA 32KB: K1(sc*src) -> VT1(sc*src). RB 32KB: K2(own) -> VT2(own).
// Order (identical to R12): stageK -> S1 -> QK -> S2 -> VT1 -> softmax(max,exp)
// -> pack P~ (no rz) -> VT2 -> S3 -> PV -> o *= shfl(rz) -> store.
__global__ __launch_bounds__(512, 4)
void k_attn(const float* __restrict__ q, const float* __restrict__ k,
            const float* __restrict__ v, const float2* __restrict__ scIdx,
            float* __restrict__ out) {
  __shared__ __align__(16) unsigned short RA[128 * 128];   // 32KB
  __shared__ __align__(16) unsigned short RB[128 * 128];   // 32KB

  int blk0 = blockIdx.x;
  int blk  = ((blk0 & 7) << 7) | (blk0 >> 3);  // XCD-chunked swizzle (1024 = 8*128)
  int u  = blk & (NB_ - 1);
  int bh = blk >> 5;
  int h  = bh & (H_ - 1);
  bool rot = (h >= HH_);
  float2 si = scIdx[bh * NB_ + u];
  float sc = si.x;
  int  src = __float_as_int(si.y);
  const size_t base = (size_t)bh * T_ * DH_;

  int tid  = threadIdx.x;
  int lane = tid & 63;
  int w    = tid >> 6;        // wave 0..7, owns q-rows [16w, 16w+16)
  int g    = lane >> 4;       // 0..3
  int c    = lane & 15;       // 0..15

  const float QSCALE = 0.03125f * 1.44269504f;   // d^-0.5 * log2e folded into Q

  // ---- Q fragments (B-operand: col = c -> i = 16w + c), pre-scaled ----
  short8 qf[4];
  {
    int t = u * BSZ_ + 16 * w + c;
    if (rot) t = (t + (BSZ_ - 1)) & (T_ - 1);
    const float* qrow = q + base + (size_t)t * DH_;
    #pragma unroll
    for (int kt = 0; kt < 4; ++kt) {
      f32x4 a = *(const f32x4*)(qrow + kt * 32 + g * 8) * QSCALE;
      f32x4 b = *(const f32x4*)(qrow + kt * 32 + g * 8 + 4) * QSCALE;
      u32x4 tt;
      tt.x = cvt_pk_bf16(a[0], a[1]);
      tt.y = cvt_pk_bf16(a[2], a[3]);
      tt.z = cvt_pk_bf16(b[0], b[1]);
      tt.w = cvt_pk_bf16(b[2], b[3]);
      qf[kt] = __builtin_bit_cast(short8, tt);
    }
  }

  // ---- Stage K halves: K1 = sc*k[src] -> RA, K2 = k[u] -> RB ----
  #pragma unroll
  for (int rep = 0; rep < 16; ++rep) {
    int chunk = tid + rep * 512;          // 8192 chunks of 4 floats
    int jr = chunk >> 5;                  // 0..255
    int c0 = (chunk & 31) * 4;
    int t; float mul;
    if (jr < BSZ_) { t = src * BSZ_ + jr;         mul = sc;  }
    else           { t = u  * BSZ_ + (jr - BSZ_); mul = 1.f; }
    if (rot) t = (t + (BSZ_ - 1)) & (T_ - 1);
    f32x4 a = *(const f32x4*)(k + base + (size_t)t * DH_ + c0) * mul;
    uint2 wv;
    wv.x = cvt_pk_bf16(a[0], a[1]);
    wv.y = cvt_pk_bf16(a[2], a[3]);
    unsigned short* Rg = (jr < BSZ_) ? RA : RB;
    int row = jr & 127;
    *(uint2*)((char*)Rg + row * 256 + ((c0 * 2) ^ ((row & 15) << 4))) = wv;
  }
  __syncthreads();   // S1

  // ---- VT staging: load -> convert -> commit immediately (transient regs only) ----
  // Column permute within each 32-j block: jc = (j&~31) | 8*((j>>2)&3) | 4*((j>>4)&1) | (j&3)
  auto vt_stage = [&](int sb, float mul, unsigned short* Rg) {
    #pragma unroll
    for (int rep = 0; rep < 2; ++rep) {
      int j0 = ((tid >> 5) + rep * 16) * 4;
      int jc0 = (j0 & ~31) | (((j0 >> 2) & 3) << 3) | (((j0 >> 4) & 1) << 2);
      int d0 = (tid & 31) * 4;
      f32x4 rr[4];
      #pragma unroll
      for (int jj = 0; jj < 4; ++jj) {
        int t = sb * BSZ_ + j0 + jj;
        if (rot) t = (t + (BSZ_ - 1)) & (T_ - 1);
        rr[jj] = *(const f32x4*)(v + base + (size_t)t * DH_ + d0) * mul;
      }
      #pragma unroll
      for (int m = 0; m < 4; ++m) {
        uint2 wv;
        wv.x = cvt_pk_bf16(rr[0][m], rr[1][m]);
        wv.y = cvt_pk_bf16(rr[2][m], rr[3][m]);
        int row = d0 + m;
        *(uint2*)((char*)Rg + row * 256 + ((jc0 * 2) ^ ((row & 15) << 4))) = wv;
      }
    }
  };

  const bool lastrot = rot && (u == NB_ - 1);
  const int i = 16 * w + c;
  const bool killLow = lastrot && (i > 0);

  // ---- QK^T swapped: acc[jt][r] = S[j = 16jt+4g+r][i = 16w+c]; skip jt > 8+w ----
  f32x4 acc[16];
  #pragma unroll
  for (int jt = 0; jt < 16; ++jt) acc[jt] = f32x4{0.f, 0.f, 0.f, 0.f};

  __builtin_amdgcn_s_setprio(1);
  #pragma unroll
  for (int kt = 0; kt < 4; ++kt) {
    #pragma unroll
    for (int jt = 0; jt < 16; ++jt) {
      if (jt <= 8 + w) {
        const unsigned short* Rg = (jt < 8) ? RA : RB;
        int row = (jt & 7) * 16 + c;
        short8 bfr = *(const short8*)((const char*)Rg + row * 256 + ((kt * 64 + g * 16) ^ ((row & 15) << 4)));
        acc[jt] = __builtin_amdgcn_mfma_f32_16x16x32_bf16(bfr, qf[kt], acc[jt], 0, 0, 0);
      }
    }
  }
  __builtin_amdgcn_s_setprio(0);

  __syncthreads();   // S2 (K reads done; RA/RB free)

  vt_stage(src, sc, RA);       // VT1 = sc*v[src] -> RA; loads hide under softmax

  // ---- mask + softmax max/exp (scores fully pre-scaled); skipped tiles stay 0 ----
  float mx = -3.4e38f;
  #pragma unroll
  for (int jt = 0; jt < 16; ++jt) {
    if (jt <= 8 + w) {
      #pragma unroll
      for (int r = 0; r < 4; ++r) {
        float s = acc[jt][r];
        bool vis;
        if (jt < 8) {
          vis = !killLow;
        } else {
          int jb = 16 * (jt - 8) + 4 * g + r;
          vis = (i >= jb);
          if (jt == 8) vis = vis && !(killLow && (g == 0) && (r == 0));
        }
        s = vis ? s : -3.4e38f;
        acc[jt][r] = s;
        mx = fmaxf(mx, s);
      }
    }
  }
  mx = fmaxf(mx, __shfl_xor(mx, 16));
  mx = fmaxf(mx, __shfl_xor(mx, 32));
  float zs = 0.f;
  #pragma unroll
  for (int jt = 0; jt < 16; ++jt) {
    if (jt <= 8 + w) {
      #pragma unroll
      for (int r = 0; r < 4; ++r) {
        float p = exp2f(acc[jt][r] - mx);
        acc[jt][r] = p;
        zs += p;
      }
    }
  }
  // zs reduction overlaps the pack below (pack no longer depends on rz)
  zs += __shfl_xor(zs, 16);
  zs += __shfl_xor(zs, 32);

  // ---- P A-frags: UNNORMALIZED pack (rz applied post-PV); skip masked own-half m ----
  short8 pa[8];
  #pragma unroll
  for (int m = 0; m < 8; ++m) {
    if (m < 4 || (m - 4) <= (w >> 1)) {
      u32x4 tt;
      tt.x = cvt_pk_bf16(acc[2 * m][0],     acc[2 * m][1]);
      tt.y = cvt_pk_bf16(acc[2 * m][2],     acc[2 * m][3]);
      tt.z = cvt_pk_bf16(acc[2 * m + 1][0], acc[2 * m + 1][1]);
      tt.w = cvt_pk_bf16(acc[2 * m + 1][2], acc[2 * m + 1][3]);
      pa[m] = __builtin_bit_cast(short8, tt);
    }
  }
  float rz = 1.f / zs;

  vt_stage(u, 1.f, RB);        // VT2 = v[u] -> RB (loads overlap pack / other waves)
  __syncthreads();   // S3

  // ---- PV: accumulate into acc[0..7]; skip own-half m with all-zero P ----
  #pragma unroll
  for (int nt = 0; nt < 8; ++nt) acc[nt] = f32x4{0.f, 0.f, 0.f, 0.f};

  __builtin_amdgcn_s_setprio(1);
  #pragma unroll
  for (int m = 0; m < 8; ++m) {
    if (m < 4 || (m - 4) <= (w >> 1)) {
      const unsigned short* Rg = (m < 4) ? RA : RB;
      int mloc = m & 3;
      #pragma unroll
      for (int nt = 0; nt < 8; ++nt) {
        int vrow = nt * 16 + c;
        short8 vb = *(const short8*)((const char*)Rg + vrow * 256 + ((mloc * 64 + g * 16) ^ ((vrow & 15) << 4)));
        acc[nt] = __builtin_amdgcn_mfma_f32_16x16x32_bf16(pa[m], vb, acc[nt], 0, 0, 0);
      }
    }
  }
  __builtin_amdgcn_s_setprio(0);

  // ---- normalize per output row (rz lives in lane of row i=16w+c -> shuffle) ----
  #pragma unroll
  for (int r = 0; r < 4; ++r) {
    float fr = __shfl(rz, 16 * (lane >> 4) /*dummy keep width*/ >= 0 ? (4 * g + r) : 0);
    #pragma unroll
    for (int nt = 0; nt < 8; ++nt) acc[nt][r] *= fr;
  }

  // ---- store (undo rotation); acc[nt][r] = O[i=16w+4g+r][d=16nt+c] ----
  #pragma unroll
  for (int r = 0; r < 4; ++r) {
    int il = 4 * g + r;
    int t = u * BSZ_ + 16 * w + il;
    if (rot) t = (t + (BSZ_ - 1)) & (T_ - 1);
    float* orow = out + base + (size_t)t * DH_;
    #pragma unroll
    for (int nt = 0; nt < 8; ++nt) {
      orow[nt * 16 + c] = acc[nt][r];
    }
  }
}

extern "C" void kernel_launch(void* const* d_in, const int* in_sizes, int n_in,
                              void* d_out, int out_size, void* d_ws, size_t ws_size,
                              hipStream_t stream) {
  const float* q = (const float*)d_in[0];
  const float* k = (const float*)d_in[1];
  const float* v = (const float*)d_in[2];
  const float* W = (const float*)d_in[3];
  float* out = (float*)d_out;

  float*  bucketsum = (float*)d_ws;                 // 131072 floats
  float*  firstrow  = bucketsum + 131072;           // 131072 floats
  float2* scIdx     = (float2*)(firstrow + 131072); // 1024 float2

  k_bucket_sums<<<BH_ * NB_, 256, 0, stream>>>(k, bucketsum, firstrow);
  k_routing<<<BH_, 256, 0, stream>>>(W, bucketsum, firstrow, scIdx);
  k_attn<<<BH_ * NB_, 512, 0, stream>>>(q, k, v, scIdx, out);
}

// Round 15
// 74.128 us; speedup vs baseline: 1.1059x; 1.0262x over previous
//
#include <hip/hip_runtime.h>

// Problem constants
constexpr int T_    = 4096;
constexpr int DH_   = 128;
constexpr int NB_   = 32;    // buckets
constexpr int BSZ_  = 128;   // bucket size
constexpr int HH_   = 4;     // H/2 (rotated heads start here)
constexpr int H_    = 8;
constexpr int BH_   = 32;    // B*H

typedef __attribute__((ext_vector_type(8))) short short8;
typedef __attribute__((ext_vector_type(4))) float f32x4;
typedef __attribute__((ext_vector_type(4))) unsigned int u32x4;

__device__ __forceinline__ unsigned int cvt_pk_bf16(float lo, float hi) {
  unsigned int r;
  asm("v_cvt_pk_bf16_f32 %0, %1, %2" : "=v"(r) : "v"(lo), "v"(hi));
  return r;
}

// ---------------- Kernel A1: per-bucket column sums + first row (conflict-free reduce) --
__global__ __launch_bounds__(256)
void k_bucket_sums(const float* __restrict__ k,
                   float* __restrict__ bucketsum,
                   float* __restrict__ firstrow) {
  // planar reduce arrays: 4B lane stride -> no LDS bank conflicts
  __shared__ float redx[8][32], redy[8][32], redz[8][32], redw[8][32];
  int blk = blockIdx.x;           // (b*H + h)*NB + u
  int u = blk & (NB_ - 1);
  int bh = blk >> 5;
  int h = bh & (H_ - 1);
  bool rot = (h >= HH_);
  int tid = threadIdx.x;
  int rq = tid >> 5;              // 0..7
  int l  = tid & 31;              // 0..31
  int d0 = l * 4;
  const float* kb = k + (size_t)bh * T_ * DH_;

  float4 s = {0.f, 0.f, 0.f, 0.f};
  float4 first = {0.f, 0.f, 0.f, 0.f};
  #pragma unroll
  for (int it = 0; it < 16; ++it) {
    int i = it * 8 + rq;
    int t = u * BSZ_ + i;
    if (rot) t = (t + (BSZ_ - 1)) & (T_ - 1);
    float4 a = *(const float4*)(kb + (size_t)t * DH_ + d0);
    s.x += a.x; s.y += a.y; s.z += a.z; s.w += a.w;
    if (it == 0 && rq == 0) first = a;
  }
  redx[rq][l] = s.x; redy[rq][l] = s.y; redz[rq][l] = s.z; redw[rq][l] = s.w;
  __syncthreads();
  if (rq == 0) {
    float4 acc = {0.f, 0.f, 0.f, 0.f};
    #pragma unroll
    for (int j = 0; j < 8; ++j) {
      acc.x += redx[j][l]; acc.y += redy[j][l];
      acc.z += redz[j][l]; acc.w += redw[j][l];
    }
    *(float4*)(bucketsum + (size_t)blk * DH_ + d0) = acc;
    *(float4*)(firstrow  + (size_t)blk * DH_ + d0) = first;
  }
}

// ---------------- Kernel A2: routing (LDS-preloaded inputs, then cumsum) ----------------
__global__ __launch_bounds__(256)
void k_routing(const float* __restrict__ W,
               const float* __restrict__ bucketsum,
               const float* __restrict__ firstrow,
               float2* __restrict__ scIdx) {
  __shared__ float Wl[2 * DH_ * NB_];      // [e][v] row-major, 8192 floats (32KB)
  __shared__ float BSl[NB_ * DH_];         // bucketsum preload (16KB)
  __shared__ float FRl[NB_ * DH_];         // firstrow preload (16KB)
  __shared__ float Xl[NB_][2 * DH_ + 1];   // padded (33KB)
  __shared__ float Rl[NB_][36];            // 4.6KB
  int bh = blockIdx.x;
  int h = bh & (H_ - 1);
  int tid = threadIdx.x;                   // 256 threads

  const float4* Wg = (const float4*)(W + (size_t)h * 2 * DH_ * NB_);
  #pragma unroll
  for (int rep = 0; rep < 8; ++rep)
    ((float4*)Wl)[tid + rep * 256] = Wg[tid + rep * 256];

  // cooperative preload: pipelined float4 loads instead of 32 serial latency hops
  const float4* BSg = (const float4*)(bucketsum + (size_t)bh * NB_ * DH_);
  const float4* FRg = (const float4*)(firstrow  + (size_t)bh * NB_ * DH_);
  #pragma unroll
  for (int rep = 0; rep < 4; ++rep) {
    ((float4*)BSl)[tid + rep * 256] = BSg[tid + rep * 256];
    ((float4*)FRl)[tid + rep * 256] = FRg[tid + rep * 256];
  }
  __syncthreads();

  if (tid < DH_) {
    int d = tid;
    float S = 0.f;
    for (int u = 0; u < NB_; ++u) {
      float fr = FRl[u * DH_ + d];
      float bs = BSl[u * DH_ + d];
      Xl[u][d]        = (S + fr) / (float)(u * BSZ_ + 1);
      Xl[u][DH_ + d]  = fr;
      S += bs;
    }
  }
  __syncthreads();

  {
    int u = tid >> 3;
    int vg = tid & 7;
    float4 racc = {0.f, 0.f, 0.f, 0.f};
    for (int e = 0; e < 2 * DH_; ++e) {
      float xv = Xl[u][e];
      float4 wv = *(const float4*)(Wl + e * NB_ + vg * 4);
      racc.x += xv * wv.x; racc.y += xv * wv.y;
      racc.z += xv * wv.z; racc.w += xv * wv.w;
    }
    racc.x = (racc.x > 0.f) ? racc.x : 0.01f * racc.x;
    racc.y = (racc.y > 0.f) ? racc.y : 0.01f * racc.y;
    racc.z = (racc.z > 0.f) ? racc.z : 0.01f * racc.z;
    racc.w = (racc.w > 0.f) ? racc.w : 0.01f * racc.w;
    *(float4*)(&Rl[u][vg * 4]) = racc;
  }
  __syncthreads();

  if (tid < NB_) {
    int u = tid;
    float m = -3.4e38f;
    float r[NB_];
    #pragma unroll
    for (int v = 0; v < NB_; ++v) { r[v] = Rl[u][v]; m = fmaxf(m, r[v]); }
    float Z = 0.f;
    #pragma unroll
    for (int v = 0; v < NB_; ++v) Z += expf(r[v] - m);
    float best = -3.4e38f; int bi = 0;
    for (int v = 0; v < u; ++v) {        // tril(-1): only v < u survive
      if (r[v] > best) { best = r[v]; bi = v; }
    }
    float sc = (u == 0) ? 0.f : expf(best - m) / Z;
    int  idx = (u == 0) ? 0 : bi;
    scIdx[bh * NB_ + u] = make_float2(sc, __int_as_float(idx));
  }
}

// ---------------- Kernel B: R12 exact (frozen best: 67 us, WRITE clean) ----------------
// RA 32KB: K1(sc*src) -> VT1(sc*src). RB 32KB: K2(own) -> VT2(own).
// Q carries d^-0.5*log2e; softmax pure max/exp/sum, single rz; causal tile skipping;
// PV accumulates into acc[0..7].
__global__ __launch_bounds__(512, 4)
void k_attn(const float* __restrict__ q, const float* __restrict__ k,
            const float* __restrict__ v, const float2* __restrict__ scIdx,
            float* __restrict__ out) {
  __shared__ __align__(16) unsigned short RA[128 * 128];   // 32KB
  __shared__ __align__(16) unsigned short RB[128 * 128];   // 32KB

  int blk0 = blockIdx.x;
  int blk  = ((blk0 & 7) << 7) | (blk0 >> 3);  // XCD-chunked swizzle (1024 = 8*128)
  int u  = blk & (NB_ - 1);
  int bh = blk >> 5;
  int h  = bh & (H_ - 1);
  bool rot = (h >= HH_);
  float2 si = scIdx[bh * NB_ + u];
  float sc = si.x;
  int  src = __float_as_int(si.y);
  const size_t base = (size_t)bh * T_ * DH_;

  int tid  = threadIdx.x;
  int lane = tid & 63;
  int w    = tid >> 6;        // wave 0..7, owns q-rows [16w, 16w+16)
  int g    = lane >> 4;       // 0..3
  int c    = lane & 15;       // 0..15

  const float QSCALE = 0.03125f * 1.44269504f;   // d^-0.5 * log2e folded into Q

  // ---- Q fragments (B-operand: col = c -> i = 16w + c), pre-scaled ----
  short8 qf[4];
  {
    int t = u * BSZ_ + 16 * w + c;
    if (rot) t = (t + (BSZ_ - 1)) & (T_ - 1);
    const float* qrow = q + base + (size_t)t * DH_;
    #pragma unroll
    for (int kt = 0; kt < 4; ++kt) {
      f32x4 a = *(const f32x4*)(qrow + kt * 32 + g * 8) * QSCALE;
      f32x4 b = *(const f32x4*)(qrow + kt * 32 + g * 8 + 4) * QSCALE;
      u32x4 tt;
      tt.x = cvt_pk_bf16(a[0], a[1]);
      tt.y = cvt_pk_bf16(a[2], a[3]);
      tt.z = cvt_pk_bf16(b[0], b[1]);
      tt.w = cvt_pk_bf16(b[2], b[3]);
      qf[kt] = __builtin_bit_cast(short8, tt);
    }
  }

  // ---- Stage K halves: K1 = sc*k[src] -> RA, K2 = k[u] -> RB ----
  #pragma unroll
  for (int rep = 0; rep < 16; ++rep) {
    int chunk = tid + rep * 512;          // 8192 chunks of 4 floats
    int jr = chunk >> 5;                  // 0..255
    int c0 = (chunk & 31) * 4;
    int t; float mul;
    if (jr < BSZ_) { t = src * BSZ_ + jr;         mul = sc;  }
    else           { t = u  * BSZ_ + (jr - BSZ_); mul = 1.f; }
    if (rot) t = (t + (BSZ_ - 1)) & (T_ - 1);
    f32x4 a = *(const f32x4*)(k + base + (size_t)t * DH_ + c0) * mul;
    uint2 wv;
    wv.x = cvt_pk_bf16(a[0], a[1]);
    wv.y = cvt_pk_bf16(a[2], a[3]);
    unsigned short* Rg = (jr < BSZ_) ? RA : RB;
    int row = jr & 127;
    *(uint2*)((char*)Rg + row * 256 + ((c0 * 2) ^ ((row & 15) << 4))) = wv;
  }
  __syncthreads();   // S1

  // ---- VT staging: load -> convert -> commit immediately (transient regs only) ----
  // Column permute within each 32-j block: jc = (j&~31) | 8*((j>>2)&3) | 4*((j>>4)&1) | (j&3)
  auto vt_stage = [&](int sb, float mul, unsigned short* Rg) {
    #pragma unroll
    for (int rep = 0; rep < 2; ++rep) {
      int j0 = ((tid >> 5) + rep * 16) * 4;
      int jc0 = (j0 & ~31) | (((j0 >> 2) & 3) << 3) | (((j0 >> 4) & 1) << 2);
      int d0 = (tid & 31) * 4;
      f32x4 rr[4];
      #pragma unroll
      for (int jj = 0; jj < 4; ++jj) {
        int t = sb * BSZ_ + j0 + jj;
        if (rot) t = (t + (BSZ_ - 1)) & (T_ - 1);
        rr[jj] = *(const f32x4*)(v + base + (size_t)t * DH_ + d0) * mul;
      }
      #pragma unroll
      for (int m = 0; m < 4; ++m) {
        uint2 wv;
        wv.x = cvt_pk_bf16(rr[0][m], rr[1][m]);
        wv.y = cvt_pk_bf16(rr[2][m], rr[3][m]);
        int row = d0 + m;
        *(uint2*)((char*)Rg + row * 256 + ((jc0 * 2) ^ ((row & 15) << 4))) = wv;
      }
    }
  };

  const bool lastrot = rot && (u == NB_ - 1);
  const int i = 16 * w + c;
  const bool killLow = lastrot && (i > 0);

  // ---- QK^T swapped: acc[jt][r] = S[j = 16jt+4g+r][i = 16w+c]; skip jt > 8+w ----
  f32x4 acc[16];
  #pragma unroll
  for (int jt = 0; jt < 16; ++jt) acc[jt] = f32x4{0.f, 0.f, 0.f, 0.f};

  __builtin_amdgcn_s_setprio(1);
  #pragma unroll
  for (int kt = 0; kt < 4; ++kt) {
    #pragma unroll
    for (int jt = 0; jt < 16; ++jt) {
      if (jt <= 8 + w) {
        const unsigned short* Rg = (jt < 8) ? RA : RB;
        int row = (jt & 7) * 16 + c;
        short8 bfr = *(const short8*)((const char*)Rg + row * 256 + ((kt * 64 + g * 16) ^ ((row & 15) << 4)));
        acc[jt] = __builtin_amdgcn_mfma_f32_16x16x32_bf16(bfr, qf[kt], acc[jt], 0, 0, 0);
      }
    }
  }
  __builtin_amdgcn_s_setprio(0);

  __syncthreads();   // S2 (K reads done; RA/RB free)

  vt_stage(src, sc, RA);       // VT1 = sc*v[src] -> RA; loads hide under softmax

  // ---- mask + softmax (scores fully pre-scaled); skipped tiles stay 0 ----
  float mx = -3.4e38f;
  #pragma unroll
  for (int jt = 0; jt < 16; ++jt) {
    if (jt <= 8 + w) {
      #pragma unroll
      for (int r = 0; r < 4; ++r) {
        float s = acc[jt][r];
        bool vis;
        if (jt < 8) {
          vis = !killLow;
        } else {
          int jb = 16 * (jt - 8) + 4 * g + r;
          vis = (i >= jb);
          if (jt == 8) vis = vis && !(killLow && (g == 0) && (r == 0));
        }
        s = vis ? s : -3.4e38f;
        acc[jt][r] = s;
        mx = fmaxf(mx, s);
      }
    }
  }
  mx = fmaxf(mx, __shfl_xor(mx, 16));
  mx = fmaxf(mx, __shfl_xor(mx, 32));
  float zs = 0.f;
  #pragma unroll
  for (int jt = 0; jt < 16; ++jt) {
    if (jt <= 8 + w) {
      #pragma unroll
      for (int r = 0; r < 4; ++r) {
        float p = exp2f(acc[jt][r] - mx);
        acc[jt][r] = p;
        zs += p;
      }
    }
  }
  zs += __shfl_xor(zs, 16);
  zs += __shfl_xor(zs, 32);
  float rz = 1.f / zs;

  vt_stage(u, 1.f, RB);        // VT2 = v[u] -> RB (loads overlap softmax tail / pack)

  // ---- P A-frags: register repack, uniform rz; skip fully-masked own-half m ----
  short8 pa[8];
  #pragma unroll
  for (int m = 0; m < 8; ++m) {
    if (m < 4 || (m - 4) <= (w >> 1)) {
      u32x4 tt;
      tt.x = cvt_pk_bf16(acc[2 * m][0] * rz,     acc[2 * m][1] * rz);
      tt.y = cvt_pk_bf16(acc[2 * m][2] * rz,     acc[2 * m][3] * rz);
      tt.z = cvt_pk_bf16(acc[2 * m + 1][0] * rz, acc[2 * m + 1][1] * rz);
      tt.w = cvt_pk_bf16(acc[2 * m + 1][2] * rz, acc[2 * m + 1][3] * rz);
      pa[m] = __builtin_bit_cast(short8, tt);
    }
  }
  __syncthreads();   // S3

  // ---- PV: accumulate into acc[0..7]; skip own-half m with all-zero P ----
  #pragma unroll
  for (int nt = 0; nt < 8; ++nt) acc[nt] = f32x4{0.f, 0.f, 0.f, 0.f};

  __builtin_amdgcn_s_setprio(1);
  #pragma unroll
  for (int m = 0; m < 8; ++m) {
    if (m < 4 || (m - 4) <= (w >> 1)) {
      const unsigned short* Rg = (m < 4) ? RA : RB;
      int mloc = m & 3;
      #pragma unroll
      for (int nt = 0; nt < 8; ++nt) {
        int vrow = nt * 16 + c;
        short8 vb = *(const short8*)((const char*)Rg + vrow * 256 + ((mloc * 64 + g * 16) ^ ((vrow & 15) << 4)));
        acc[nt] = __builtin_amdgcn_mfma_f32_16x16x32_bf16(pa[m], vb, acc[nt], 0, 0, 0);
      }
    }
  }
  __builtin_amdgcn_s_setprio(0);

  // ---- store (undo rotation); acc[nt][r] = O[i=16w+4g+r][d=16nt+c] ----
  #pragma unroll
  for (int r = 0; r < 4; ++r) {
    int il = 4 * g + r;
    int t = u * BSZ_ + 16 * w + il;
    if (rot) t = (t + (BSZ_ - 1)) & (T_ - 1);
    float* orow = out + base + (size_t)t * DH_;
    #pragma unroll
    for (int nt = 0; nt < 8; ++nt) {
      orow[nt * 16 + c] = acc[nt][r];
    }
  }
}

extern "C" void kernel_launch(void* const* d_in, const int* in_sizes, int n_in,
                              void* d_out, int out_size, void* d_ws, size_t ws_size,
                              hipStream_t stream) {
  const float* q = (const float*)d_in[0];
  const float* k = (const float*)d_in[1];
  const float* v = (const float*)d_in[2];
  const float* W = (const float*)d_in[3];
  float* out = (float*)d_out;

  float*  bucketsum = (float*)d_ws;                 // 131072 floats
  float*  firstrow  = bucketsum + 131072;           // 131072 floats
  float2* scIdx     = (float2*)(firstrow + 131072); // 1024 float2

  k_bucket_sums<<<BH_ * NB_, 256, 0, stream>>>(k, bucketsum, firstrow);
  k_routing<<<BH_, 256, 0, stream>>>(W, bucketsum, firstrow, scIdx);
  k_attn<<<BH_ * NB_, 512, 0, stream>>>(q, k, v, scIdx, out);
}